// Round 1
// baseline (978.360 us; speedup 1.0000x reference)
//
#include <hip/hip_runtime.h>

#define NN 100000
#define NE 1600000
#define D  128
#define SCAN_CHUNK 1024
#define NSCAN ((NN + SCAN_CHUNK - 1) / SCAN_CHUNK)   // 98
#define TM 64

__device__ inline float dot4(float4 a, float4 b) {
    return a.x*b.x + a.y*b.y + a.z*b.z + a.w*b.w;
}

__global__ void zero_int(int* __restrict__ p, int n) {
    int i = blockIdx.x * 256 + threadIdx.x;
    if (i < n) p[i] = 0;
}

__global__ void copy_int(const int* __restrict__ a, int* __restrict__ b, int n) {
    int i = blockIdx.x * 256 + threadIdx.x;
    if (i < n) b[i] = a[i];
}

// count in-degree: cnt[dst]++
__global__ void hist_kernel(const int* __restrict__ ei, int* __restrict__ cnt) {
    int e = blockIdx.x * 256 + threadIdx.x;
    if (e < NE) atomicAdd(&cnt[ei[NE + e]], 1);
}

// per-1024-chunk exclusive scan, emit chunk sums
__global__ void scanA(const int* __restrict__ cnt, int* __restrict__ rowptr,
                      int* __restrict__ bsum) {
    __shared__ int lds[256];
    int tid  = threadIdx.x;
    int base = blockIdx.x * SCAN_CHUNK + tid * 4;
    int v[4];
#pragma unroll
    for (int i = 0; i < 4; ++i) v[i] = (base + i < NN) ? cnt[base + i] : 0;
    int s = v[0] + v[1] + v[2] + v[3];
    lds[tid] = s;
    __syncthreads();
    for (int off = 1; off < 256; off <<= 1) {
        int t = (tid >= off) ? lds[tid - off] : 0;
        __syncthreads();
        lds[tid] += t;
        __syncthreads();
    }
    int excl = lds[tid] - s;   // exclusive prefix of this thread within block
    if (tid == 255) bsum[blockIdx.x] = lds[255];
    int run = excl;
#pragma unroll
    for (int i = 0; i < 4; ++i) {
        if (base + i < NN) rowptr[base + i] = run;
        run += v[i];
    }
}

// scan the 98 chunk sums (tiny, sequential)
__global__ void scanB(int* __restrict__ bsum, int nb) {
    if (threadIdx.x == 0 && blockIdx.x == 0) {
        int run = 0;
        for (int i = 0; i < nb; ++i) { int t = bsum[i]; bsum[i] = run; run += t; }
    }
}

__global__ void scanC(int* __restrict__ rowptr, const int* __restrict__ bsum) {
    int i = blockIdx.x * 256 + threadIdx.x;
    if (i < NN) rowptr[i] += bsum[i / SCAN_CHUNK];
    if (i == 0) rowptr[NN] = NE;
}

// scatter edges into CSR col array
__global__ void fill_csr(const int* __restrict__ ei, int* __restrict__ cursor,
                         int* __restrict__ col) {
    int e = blockIdx.x * 256 + threadIdx.x;
    if (e < NE) {
        int s = ei[e];
        int d = ei[NE + e];
        int pos = atomicAdd(&cursor[d], 1);
        col[pos] = s;
    }
}

// mean aggregation: one 64-lane wave per node, float2 per lane (128 floats/row)
__global__ __launch_bounds__(256) void aggregate(const float* __restrict__ h,
                                                 const int* __restrict__ rowptr,
                                                 const int* __restrict__ col,
                                                 float* __restrict__ agg) {
    int node = blockIdx.x * 4 + (threadIdx.x >> 6);
    if (node >= NN) return;
    int lane = threadIdx.x & 63;
    int beg = rowptr[node], end = rowptr[node + 1];
    const float2* hp = (const float2*)h;
    float ax = 0.f, ay = 0.f;
    int j = beg;
    for (; j + 3 < end; j += 4) {
        int c0 = col[j], c1 = col[j + 1], c2 = col[j + 2], c3 = col[j + 3];
        float2 v0 = hp[c0 * 64 + lane];
        float2 v1 = hp[c1 * 64 + lane];
        float2 v2 = hp[c2 * 64 + lane];
        float2 v3 = hp[c3 * 64 + lane];
        ax += v0.x + v1.x + v2.x + v3.x;
        ay += v0.y + v1.y + v2.y + v3.y;
    }
    for (; j < end; ++j) {
        int c = col[j];
        float2 v = hp[c * 64 + lane];
        ax += v.x; ay += v.y;
    }
    int deg = end - beg;
    float inv = 1.0f / (float)(deg > 1 ? deg : 1);
    float2 r; r.x = ax * inv; r.y = ay * inv;
    ((float2*)agg)[node * 64 + lane] = r;
}

// out[n][j] = leaky_relu( sum_k agg[n][k]*Wl[j][k] + hin[n][k]*Wr[j][k] + b[j], 0.5 )
// 256 threads: 64-row tile, thread = (row-quarter mh = tid>>6) x (col pair j0 = (tid&63)*2)
__global__ __launch_bounds__(256) void sage_gemm(const float* __restrict__ agg,
                                                 const float* __restrict__ hin,
                                                 const float* __restrict__ Wl,
                                                 const float* __restrict__ Wr,
                                                 const float* __restrict__ bias,
                                                 float* __restrict__ out) {
    __shared__ float sA[TM][D];   // 32 KB
    __shared__ float sH[TM][D];   // 32 KB
    int block0 = blockIdx.x * TM;
    int nrows = NN - block0; if (nrows > TM) nrows = TM;

    const float4* av = (const float4*)(agg + (size_t)block0 * D);
    const float4* hv = (const float4*)(hin + (size_t)block0 * D);
    float4* sAv = (float4*)sA;
    float4* sHv = (float4*)sH;
    for (int i = threadIdx.x; i < nrows * (D / 4); i += 256) {
        sAv[i] = av[i];
        sHv[i] = hv[i];
    }
    __syncthreads();

    int lane_j = threadIdx.x & 63;     // column pair index
    int j0 = lane_j * 2;
    int mh = threadIdx.x >> 6;         // row quarter: rows [mh*16, mh*16+16)

    const float4* wlA = (const float4*)(Wl + (size_t)j0 * D);
    const float4* wlB = (const float4*)(Wl + (size_t)(j0 + 1) * D);
    const float4* wrA = (const float4*)(Wr + (size_t)j0 * D);
    const float4* wrB = (const float4*)(Wr + (size_t)(j0 + 1) * D);

    float2 acc[16];
#pragma unroll
    for (int m = 0; m < 16; ++m) { acc[m].x = 0.f; acc[m].y = 0.f; }

#pragma unroll 1
    for (int k4 = 0; k4 < 8; ++k4) {          // 16 k per iteration
        float4 la[4], lb[4], ra[4], rb[4];
#pragma unroll
        for (int q = 0; q < 4; ++q) {
            la[q] = wlA[k4 * 4 + q];
            lb[q] = wlB[k4 * 4 + q];
            ra[q] = wrA[k4 * 4 + q];
            rb[q] = wrB[k4 * 4 + q];
        }
#pragma unroll 4
        for (int m = 0; m < 16; ++m) {
            int row = mh * 16 + m;
            const float4* a4 = (const float4*)(&sA[row][k4 * 16]);
            const float4* h4 = (const float4*)(&sH[row][k4 * 16]);
            float4 a0 = a4[0], a1 = a4[1], a2 = a4[2], a3 = a4[3];
            float4 h0 = h4[0], h1 = h4[1], h2 = h4[2], h3 = h4[3];
            acc[m].x += dot4(a0, la[0]) + dot4(a1, la[1]) + dot4(a2, la[2]) + dot4(a3, la[3])
                      + dot4(h0, ra[0]) + dot4(h1, ra[1]) + dot4(h2, ra[2]) + dot4(h3, ra[3]);
            acc[m].y += dot4(a0, lb[0]) + dot4(a1, lb[1]) + dot4(a2, lb[2]) + dot4(a3, lb[3])
                      + dot4(h0, rb[0]) + dot4(h1, rb[1]) + dot4(h2, rb[2]) + dot4(h3, rb[3]);
        }
    }

    float2 bj = ((const float2*)bias)[lane_j];
#pragma unroll
    for (int m = 0; m < 16; ++m) {
        int row = mh * 16 + m;
        if (block0 + row < NN) {
            float vx = acc[m].x + bj.x;
            float vy = acc[m].y + bj.y;
            vx = vx > 0.f ? vx : 0.5f * vx;
            vy = vy > 0.f ? vy : 0.5f * vy;
            float2 r; r.x = vx; r.y = vy;
            *(float2*)(out + (size_t)(block0 + row) * D + j0) = r;
        }
    }
}

extern "C" void kernel_launch(void* const* d_in, const int* in_sizes, int n_in,
                              void* d_out, int out_size, void* d_ws, size_t ws_size,
                              hipStream_t stream) {
    const float* x   = (const float*)d_in[0];
    const int*   ei  = (const int*)d_in[1];
    const float* W1l = (const float*)d_in[2];
    const float* W1r = (const float*)d_in[3];
    const float* b1  = (const float*)d_in[4];
    const float* W2l = (const float*)d_in[5];
    const float* W2r = (const float*)d_in[6];
    const float* b2  = (const float*)d_in[7];
    float* out = (float*)d_out;

    char* ws = (char*)d_ws;
    size_t off = 0;
    int* rowptr = (int*)(ws + off); off += (((size_t)(NN + 1) * 4) + 255) & ~(size_t)255;
    int* cursor = (int*)(ws + off); off += (((size_t)NN * 4) + 255) & ~(size_t)255;
    int* bsum   = (int*)(ws + off); off += 4096;
    int* col    = (int*)(ws + off); off += (size_t)NE * 4;
    float* agg  = (float*)(ws + off); off += (size_t)NN * D * 4;
    float* h1   = (float*)(ws + off); off += (size_t)NN * D * 4;

    // ---- CSR build (deterministic per call) ----
    zero_int<<<(NN + 255) / 256, 256, 0, stream>>>(cursor, NN);
    hist_kernel<<<(NE + 255) / 256, 256, 0, stream>>>(ei, cursor);
    scanA<<<NSCAN, 256, 0, stream>>>(cursor, rowptr, bsum);
    scanB<<<1, 64, 0, stream>>>(bsum, NSCAN);
    scanC<<<(NN + 255) / 256, 256, 0, stream>>>(rowptr, bsum);
    copy_int<<<(NN + 255) / 256, 256, 0, stream>>>(rowptr, cursor, NN);
    fill_csr<<<(NE + 255) / 256, 256, 0, stream>>>(ei, cursor, col);

    // ---- layer 1 ----
    aggregate<<<(NN + 3) / 4, 256, 0, stream>>>(x, rowptr, col, agg);
    sage_gemm<<<(NN + TM - 1) / TM, 256, 0, stream>>>(agg, x, W1l, W1r, b1, h1);

    // ---- layer 2 ----
    aggregate<<<(NN + 3) / 4, 256, 0, stream>>>(h1, rowptr, col, agg);
    sage_gemm<<<(NN + TM - 1) / TM, 256, 0, stream>>>(agg, h1, W2l, W2r, b2, out);
}

// Round 5
// 454.337 us; speedup vs baseline: 2.1534x; 2.1534x over previous
//
#include <hip/hip_runtime.h>
#include <hip/hip_bf16.h>

#define NN 100000
#define NE 1600000
#define D  128
#define SCAN_CHUNK 1024
#define NSCAN ((NN + SCAN_CHUNK - 1) / SCAN_CHUNK)   // 98

typedef short bf16x8 __attribute__((ext_vector_type(8)));
typedef float f32x4 __attribute__((ext_vector_type(4)));

static __device__ inline unsigned short f2b(float f) {
    __hip_bfloat16 b = __float2bfloat16(f);   // RNE
    unsigned short u;
    __builtin_memcpy(&u, &b, 2);
    return u;
}

__global__ void zero_int(int* __restrict__ p, int n) {
    int i = blockIdx.x * 256 + threadIdx.x;
    if (i < n) p[i] = 0;
}

// count in-degree: cnt[dst]++
__global__ void hist_kernel(const int* __restrict__ ei, int* __restrict__ cnt) {
    int e = blockIdx.x * 256 + threadIdx.x;
    if (e < NE) atomicAdd(&cnt[ei[NE + e]], 1);
}

// per-1024-chunk exclusive scan, emit chunk sums
__global__ void scanA(const int* __restrict__ cnt, int* __restrict__ rowptr,
                      int* __restrict__ bsum) {
    __shared__ int lds[256];
    int tid  = threadIdx.x;
    int base = blockIdx.x * SCAN_CHUNK + tid * 4;
    int v[4];
#pragma unroll
    for (int i = 0; i < 4; ++i) v[i] = (base + i < NN) ? cnt[base + i] : 0;
    int s = v[0] + v[1] + v[2] + v[3];
    lds[tid] = s;
    __syncthreads();
    for (int off = 1; off < 256; off <<= 1) {
        int t = (tid >= off) ? lds[tid - off] : 0;
        __syncthreads();
        lds[tid] += t;
        __syncthreads();
    }
    int excl = lds[tid] - s;
    if (tid == 255) bsum[blockIdx.x] = lds[255];
    int run = excl;
#pragma unroll
    for (int i = 0; i < 4; ++i) {
        if (base + i < NN) rowptr[base + i] = run;
        run += v[i];
    }
}

// parallel exclusive scan of the 98 chunk sums (one block)
__global__ void scanB(int* __restrict__ bsum, int nb) {
    __shared__ int s[128];
    int t = threadIdx.x;
    int v = (t < nb) ? bsum[t] : 0;
    s[t] = v;
    __syncthreads();
    for (int off = 1; off < 128; off <<= 1) {
        int tv = (t >= off) ? s[t - off] : 0;
        __syncthreads();
        s[t] += tv;
        __syncthreads();
    }
    if (t < nb) bsum[t] = s[t] - v;
}

// finalize rowptr and also produce the fill cursor (fused copy)
__global__ void scanC(int* __restrict__ rowptr, const int* __restrict__ bsum,
                      int* __restrict__ cursor) {
    int i = blockIdx.x * 256 + threadIdx.x;
    if (i < NN) {
        int v = rowptr[i] + bsum[i / SCAN_CHUNK];
        rowptr[i] = v;
        cursor[i] = v;
    }
    if (i == 0) rowptr[NN] = NE;
}

// scatter edges into CSR col array
__global__ void fill_csr(const int* __restrict__ ei, int* __restrict__ cursor,
                         int* __restrict__ col) {
    int e = blockIdx.x * 256 + threadIdx.x;
    if (e < NE) {
        int s = ei[e];
        int d = ei[NE + e];
        int pos = atomicAdd(&cursor[d], 1);
        col[pos] = s;
    }
}

// fp32 -> bf16 conversion, 4 elems/thread
__global__ void conv_f2b(const float* __restrict__ src,
                         unsigned short* __restrict__ dst, int n) {
    int i = (blockIdx.x * 256 + threadIdx.x) * 4;
    if (i + 3 < n) {
        float4 v = *(const float4*)(src + i);
        ushort4 o;
        o.x = f2b(v.x); o.y = f2b(v.y); o.z = f2b(v.z); o.w = f2b(v.w);
        *(ushort4*)(dst + i) = o;
    } else {
        for (; i < n; ++i) dst[i] = f2b(src[i]);
    }
}

// mean aggregation over bf16 features: one 64-lane wave per node, 2 bf16/lane
__global__ __launch_bounds__(256) void aggregate(const unsigned short* __restrict__ hb,
                                                 const int* __restrict__ rowptr,
                                                 const int* __restrict__ col,
                                                 unsigned short* __restrict__ aggb) {
    int node = blockIdx.x * 4 + (threadIdx.x >> 6);
    if (node >= NN) return;
    int lane = threadIdx.x & 63;
    int beg = rowptr[node], end = rowptr[node + 1];
    const unsigned int* hp = (const unsigned int*)hb;   // 2 bf16 per uint
    float ax = 0.f, ay = 0.f;
    int j = beg;
    for (; j + 3 < end; j += 4) {
        int c0 = col[j], c1 = col[j + 1], c2 = col[j + 2], c3 = col[j + 3];
        unsigned int v0 = hp[(size_t)c0 * 64 + lane];
        unsigned int v1 = hp[(size_t)c1 * 64 + lane];
        unsigned int v2 = hp[(size_t)c2 * 64 + lane];
        unsigned int v3 = hp[(size_t)c3 * 64 + lane];
        ax += __uint_as_float(v0 << 16) + __uint_as_float(v1 << 16)
            + __uint_as_float(v2 << 16) + __uint_as_float(v3 << 16);
        ay += __uint_as_float(v0 & 0xffff0000u) + __uint_as_float(v1 & 0xffff0000u)
            + __uint_as_float(v2 & 0xffff0000u) + __uint_as_float(v3 & 0xffff0000u);
    }
    for (; j < end; ++j) {
        unsigned int v = hp[(size_t)col[j] * 64 + lane];
        ax += __uint_as_float(v << 16);
        ay += __uint_as_float(v & 0xffff0000u);
    }
    int deg = end - beg;
    float inv = 1.0f / (float)(deg > 1 ? deg : 1);
    unsigned int pack = (unsigned int)f2b(ax * inv) | ((unsigned int)f2b(ay * inv) << 16);
    ((unsigned int*)aggb)[(size_t)node * 64 + lane] = pack;
}

// out[n][j] = leaky_relu( sum_k agg[n][k]*Wl[j][k] + h[n][k]*Wr[j][k] + b[j], 0.5 )
// MFMA 16x16x32 bf16. Block = 256 thr = 4 waves (2x2), block tile 64 rows x 128 cols,
// wave tile 32 rows x 64 cols. No LDS, no barriers: fragments load direct from global.
template <int OUT_F32>
__global__ __launch_bounds__(256) void sage_gemm_mfma(
    const unsigned short* __restrict__ Ab,   // [NN][128] aggregated
    const unsigned short* __restrict__ Hb,   // [NN][128] root
    const unsigned short* __restrict__ Wlb,  // [128][128], row j contiguous in k
    const unsigned short* __restrict__ Wrb,
    const float* __restrict__ bias,
    float* __restrict__ outf,
    unsigned short* __restrict__ outb)
{
    const int lane = threadIdx.x & 63;
    const int wid  = threadIdx.x >> 6;
    const int r  = lane & 15;
    const int kg = lane >> 4;
    const int row0 = blockIdx.x * 64 + (wid >> 1) * 32;
    const int col0 = (wid & 1) * 64;

    const int ra0 = min(row0 + r,      NN - 1);
    const int ra1 = min(row0 + 16 + r, NN - 1);

    float bv[4];
#pragma unroll
    for (int c = 0; c < 4; ++c) bv[c] = bias[col0 + c * 16 + r];

    f32x4 acc[2][4];
#pragma unroll
    for (int m = 0; m < 2; ++m)
#pragma unroll
        for (int c = 0; c < 4; ++c) acc[m][c] = (f32x4){0.f, 0.f, 0.f, 0.f};

#pragma unroll
    for (int ks = 0; ks < 8; ++ks) {
        const unsigned short* S = (ks < 4) ? Ab : Hb;
        const unsigned short* W = (ks < 4) ? Wlb : Wrb;
        const int kk = (ks & 3) * 32 + kg * 8;
        bf16x8 a0 = *(const bf16x8*)(S + (size_t)ra0 * D + kk);
        bf16x8 a1 = *(const bf16x8*)(S + (size_t)ra1 * D + kk);
        bf16x8 bw[4];
#pragma unroll
        for (int c = 0; c < 4; ++c)
            bw[c] = *(const bf16x8*)(W + (size_t)(col0 + c * 16 + r) * D + kk);
#pragma unroll
        for (int c = 0; c < 4; ++c) {
            acc[0][c] = __builtin_amdgcn_mfma_f32_16x16x32_bf16(a0, bw[c], acc[0][c], 0, 0, 0);
            acc[1][c] = __builtin_amdgcn_mfma_f32_16x16x32_bf16(a1, bw[c], acc[1][c], 0, 0, 0);
        }
    }

    // C/D layout: col = c*16 + (lane&15), row = m*16 + (lane>>4)*4 + q   [m89]
#pragma unroll
    for (int m = 0; m < 2; ++m) {
#pragma unroll
        for (int q = 0; q < 4; ++q) {
            int row = row0 + m * 16 + kg * 4 + q;
            if (row < NN) {
#pragma unroll
                for (int c = 0; c < 4; ++c) {
                    float v = acc[m][c][q] + bv[c];
                    v = v > 0.f ? v : 0.5f * v;
                    int colj = col0 + c * 16 + r;
                    if (OUT_F32) outf[(size_t)row * D + colj] = v;
                    else         outb[(size_t)row * D + colj] = f2b(v);
                }
            }
        }
    }
}

extern "C" void kernel_launch(void* const* d_in, const int* in_sizes, int n_in,
                              void* d_out, int out_size, void* d_ws, size_t ws_size,
                              hipStream_t stream) {
    const float* x   = (const float*)d_in[0];
    const int*   ei  = (const int*)d_in[1];
    const float* W1l = (const float*)d_in[2];
    const float* W1r = (const float*)d_in[3];
    const float* b1  = (const float*)d_in[4];
    const float* W2l = (const float*)d_in[5];
    const float* W2r = (const float*)d_in[6];
    const float* b2  = (const float*)d_in[7];
    float* out = (float*)d_out;

    char* ws = (char*)d_ws;
    size_t off = 0;
    auto alloc = [&](size_t bytes) {
        void* p = ws + off;
        off = (off + bytes + 255) & ~(size_t)255;
        return p;
    };
    int* rowptr = (int*)alloc((NN + 1) * 4);
    int* cursor = (int*)alloc(NN * 4);
    int* bsum   = (int*)alloc(4096);
    int* col    = (int*)alloc((size_t)NE * 4);
    unsigned short* xb   = (unsigned short*)alloc((size_t)NN * D * 2);
    unsigned short* aggb = (unsigned short*)alloc((size_t)NN * D * 2);
    unsigned short* h1b  = (unsigned short*)alloc((size_t)NN * D * 2);
    unsigned short* w1lb = (unsigned short*)alloc((size_t)D * D * 2);
    unsigned short* w1rb = (unsigned short*)alloc((size_t)D * D * 2);
    unsigned short* w2lb = (unsigned short*)alloc((size_t)D * D * 2);
    unsigned short* w2rb = (unsigned short*)alloc((size_t)D * D * 2);

    // ---- CSR build ----
    zero_int<<<(NN + 255) / 256, 256, 0, stream>>>(cursor, NN);
    hist_kernel<<<(NE + 255) / 256, 256, 0, stream>>>(ei, cursor);
    scanA<<<NSCAN, 256, 0, stream>>>(cursor, rowptr, bsum);
    scanB<<<1, 128, 0, stream>>>(bsum, NSCAN);
    scanC<<<(NN + 255) / 256, 256, 0, stream>>>(rowptr, bsum, cursor);
    fill_csr<<<(NE + 255) / 256, 256, 0, stream>>>(ei, cursor, col);

    // ---- bf16 conversions ----
    conv_f2b<<<(NN * D / 4 + 255) / 256, 256, 0, stream>>>(x, xb, NN * D);
    conv_f2b<<<(D * D / 4 + 255) / 256, 256, 0, stream>>>(W1l, w1lb, D * D);
    conv_f2b<<<(D * D / 4 + 255) / 256, 256, 0, stream>>>(W1r, w1rb, D * D);
    conv_f2b<<<(D * D / 4 + 255) / 256, 256, 0, stream>>>(W2l, w2lb, D * D);
    conv_f2b<<<(D * D / 4 + 255) / 256, 256, 0, stream>>>(W2r, w2rb, D * D);

    // ---- layer 1 ----
    aggregate<<<(NN + 3) / 4, 256, 0, stream>>>(xb, rowptr, col, aggb);
    sage_gemm_mfma<0><<<(NN + 63) / 64, 256, 0, stream>>>(aggb, xb, w1lb, w1rb, b1,
                                                          nullptr, h1b);
    // ---- layer 2 ----
    aggregate<<<(NN + 3) / 4, 256, 0, stream>>>(h1b, rowptr, col, aggb);
    sage_gemm_mfma<1><<<(NN + 63) / 64, 256, 0, stream>>>(aggb, h1b, w2lb, w2rb, b2,
                                                          out, nullptr);
}

// Round 6
// 398.079 us; speedup vs baseline: 2.4577x; 1.1413x over previous
//
#include <hip/hip_runtime.h>
#include <hip/hip_bf16.h>

#define NN 100000
#define NE 1600000
#define D  128
#define SCAN_CHUNK 1024
#define NSCAN ((NN + SCAN_CHUNK - 1) / SCAN_CHUNK)   // 98
#define NB 98          // dst buckets of 1024 nodes (dst>>10)
#define BCHUNK 8192    // edges per bin_scatter block

typedef short bf16x8 __attribute__((ext_vector_type(8)));
typedef float f32x4 __attribute__((ext_vector_type(4)));

static __device__ inline unsigned short f2b(float f) {
    __hip_bfloat16 b = __float2bfloat16(f);   // RNE
    unsigned short u;
    __builtin_memcpy(&u, &b, 2);
    return u;
}

__global__ void zero_int(int* __restrict__ p, int n) {
    int i = blockIdx.x * 256 + threadIdx.x;
    if (i < n) p[i] = 0;
}

// count in-degree: cnt[dst]++
__global__ void hist_kernel(const int* __restrict__ ei, int* __restrict__ cnt) {
    int e = blockIdx.x * 256 + threadIdx.x;
    if (e < NE) atomicAdd(&cnt[ei[NE + e]], 1);
}

// per-1024-chunk exclusive scan, emit chunk sums
__global__ void scanA(const int* __restrict__ cnt, int* __restrict__ rowptr,
                      int* __restrict__ bsum) {
    __shared__ int lds[256];
    int tid  = threadIdx.x;
    int base = blockIdx.x * SCAN_CHUNK + tid * 4;
    int v[4];
#pragma unroll
    for (int i = 0; i < 4; ++i) v[i] = (base + i < NN) ? cnt[base + i] : 0;
    int s = v[0] + v[1] + v[2] + v[3];
    lds[tid] = s;
    __syncthreads();
    for (int off = 1; off < 256; off <<= 1) {
        int t = (tid >= off) ? lds[tid - off] : 0;
        __syncthreads();
        lds[tid] += t;
        __syncthreads();
    }
    int excl = lds[tid] - s;
    if (tid == 255) bsum[blockIdx.x] = lds[255];
    int run = excl;
#pragma unroll
    for (int i = 0; i < 4; ++i) {
        if (base + i < NN) rowptr[base + i] = run;
        run += v[i];
    }
}

// parallel exclusive scan of the 98 chunk sums (one block)
__global__ void scanB(int* __restrict__ bsum, int nb) {
    __shared__ int s[128];
    int t = threadIdx.x;
    int v = (t < nb) ? bsum[t] : 0;
    s[t] = v;
    __syncthreads();
    for (int off = 1; off < 128; off <<= 1) {
        int tv = (t >= off) ? s[t - off] : 0;
        __syncthreads();
        s[t] += tv;
        __syncthreads();
    }
    if (t < nb) bsum[t] = s[t] - v;
}

// finalize rowptr; produce fill cursor (copy) and per-bucket bases gcur
__global__ void scanC(int* __restrict__ rowptr, const int* __restrict__ bsum,
                      int* __restrict__ cursor, int* __restrict__ gcur) {
    int i = blockIdx.x * 256 + threadIdx.x;
    if (i < NN) {
        int v = rowptr[i] + bsum[i / SCAN_CHUNK];
        rowptr[i] = v;
        cursor[i] = v;
        if ((i & 1023) == 0) gcur[i >> 10] = v;   // bucket base = rowptr[b<<10]
    }
    if (i == 0) rowptr[NN] = NE;
}

// Phase B: bin edges by dst>>10 into bucket-grouped (dst,src) pairs.
// Per block: LDS histogram over 98 buckets, reserve contiguous runs via one
// global atomic per bucket, then scatter. Runs are ~672B sequential -> L2
// lines fill fully -> HBM writes ~= payload (13 MB), not 64B/edge.
__global__ __launch_bounds__(256) void bin_scatter(const int* __restrict__ ei,
                                                   int* __restrict__ gcur,
                                                   unsigned long long* __restrict__ ebuf) {
    __shared__ int hist[NB];
    __shared__ int base_s[NB];
    int chunk0 = blockIdx.x * BCHUNK;
    for (int t = threadIdx.x; t < NB; t += 256) hist[t] = 0;
    __syncthreads();
    for (int i = 0; i < BCHUNK; i += 256) {
        int e = chunk0 + i + threadIdx.x;
        if (e < NE) atomicAdd(&hist[ei[NE + e] >> 10], 1);
    }
    __syncthreads();
    for (int t = threadIdx.x; t < NB; t += 256) {
        base_s[t] = atomicAdd(&gcur[t], hist[t]);
        hist[t] = 0;
    }
    __syncthreads();
    for (int i = 0; i < BCHUNK; i += 256) {
        int e = chunk0 + i + threadIdx.x;
        if (e < NE) {
            int s = ei[e];
            int d = ei[NE + e];
            int b = d >> 10;
            int off = atomicAdd(&hist[b], 1);
            ebuf[(size_t)base_s[b] + off] =
                ((unsigned long long)(unsigned)d << 32) | (unsigned)s;
        }
    }
}

// Phase C: edges are bucket-grouped; scatter src into CSR col. Each write
// lands in the current bucket's 64KB col window -> L2-resident -> ~6.4 MB HBM.
__global__ void fill_from_buckets(const unsigned long long* __restrict__ ebuf,
                                  int* __restrict__ cursor, int* __restrict__ col) {
    int e = blockIdx.x * 256 + threadIdx.x;
    if (e < NE) {
        unsigned long long p = ebuf[e];
        int s = (int)(p & 0xffffffffu);
        int d = (int)(p >> 32);
        int pos = atomicAdd(&cursor[d], 1);
        col[pos] = s;
    }
}

// fp32 -> bf16 conversion, 4 elems/thread
__global__ void conv_f2b(const float* __restrict__ src,
                         unsigned short* __restrict__ dst, int n) {
    int i = (blockIdx.x * 256 + threadIdx.x) * 4;
    if (i + 3 < n) {
        float4 v = *(const float4*)(src + i);
        ushort4 o;
        o.x = f2b(v.x); o.y = f2b(v.y); o.z = f2b(v.z); o.w = f2b(v.w);
        *(ushort4*)(dst + i) = o;
    } else {
        for (; i < n; ++i) dst[i] = f2b(src[i]);
    }
}

// all 4 weight matrices (each D*D) in one launch; dsts contiguous
__global__ void conv_w4(const float* __restrict__ s0, const float* __restrict__ s1,
                        const float* __restrict__ s2, const float* __restrict__ s3,
                        unsigned short* __restrict__ dst) {
    int i = (blockIdx.x * 256 + threadIdx.x) * 4;   // [0, 4*D*D)
    const float* srcs[4] = {s0, s1, s2, s3};
    const float* s = srcs[i >> 14];                 // D*D = 16384
    float4 v = *(const float4*)(s + (i & 16383));
    ushort4 o;
    o.x = f2b(v.x); o.y = f2b(v.y); o.z = f2b(v.z); o.w = f2b(v.w);
    *(ushort4*)(dst + i) = o;
}

// mean aggregation over bf16 features: one 64-lane wave per node, 2 bf16/lane
__global__ __launch_bounds__(256) void aggregate(const unsigned short* __restrict__ hb,
                                                 const int* __restrict__ rowptr,
                                                 const int* __restrict__ col,
                                                 unsigned short* __restrict__ aggb) {
    int node = blockIdx.x * 4 + (threadIdx.x >> 6);
    if (node >= NN) return;
    int lane = threadIdx.x & 63;
    int beg = rowptr[node], end = rowptr[node + 1];
    const unsigned int* hp = (const unsigned int*)hb;   // 2 bf16 per uint
    float ax = 0.f, ay = 0.f;
    int j = beg;
    for (; j + 3 < end; j += 4) {
        int c0 = col[j], c1 = col[j + 1], c2 = col[j + 2], c3 = col[j + 3];
        unsigned int v0 = hp[(size_t)c0 * 64 + lane];
        unsigned int v1 = hp[(size_t)c1 * 64 + lane];
        unsigned int v2 = hp[(size_t)c2 * 64 + lane];
        unsigned int v3 = hp[(size_t)c3 * 64 + lane];
        ax += __uint_as_float(v0 << 16) + __uint_as_float(v1 << 16)
            + __uint_as_float(v2 << 16) + __uint_as_float(v3 << 16);
        ay += __uint_as_float(v0 & 0xffff0000u) + __uint_as_float(v1 & 0xffff0000u)
            + __uint_as_float(v2 & 0xffff0000u) + __uint_as_float(v3 & 0xffff0000u);
    }
    for (; j < end; ++j) {
        unsigned int v = hp[(size_t)col[j] * 64 + lane];
        ax += __uint_as_float(v << 16);
        ay += __uint_as_float(v & 0xffff0000u);
    }
    int deg = end - beg;
    float inv = 1.0f / (float)(deg > 1 ? deg : 1);
    unsigned int pack = (unsigned int)f2b(ax * inv) | ((unsigned int)f2b(ay * inv) << 16);
    ((unsigned int*)aggb)[(size_t)node * 64 + lane] = pack;
}

// out[n][j] = leaky_relu( sum_k agg[n][k]*Wl[j][k] + h[n][k]*Wr[j][k] + b[j], 0.5 )
// MFMA 16x16x32 bf16. Block = 256 thr = 4 waves (2x2), block tile 64 rows x 128 cols,
// wave tile 32 rows x 64 cols. No LDS, no barriers: fragments load direct from global.
template <int OUT_F32>
__global__ __launch_bounds__(256) void sage_gemm_mfma(
    const unsigned short* __restrict__ Ab,   // [NN][128] aggregated
    const unsigned short* __restrict__ Hb,   // [NN][128] root
    const unsigned short* __restrict__ Wlb,  // [128][128], row j contiguous in k
    const unsigned short* __restrict__ Wrb,
    const float* __restrict__ bias,
    float* __restrict__ outf,
    unsigned short* __restrict__ outb)
{
    const int lane = threadIdx.x & 63;
    const int wid  = threadIdx.x >> 6;
    const int r  = lane & 15;
    const int kg = lane >> 4;
    const int row0 = blockIdx.x * 64 + (wid >> 1) * 32;
    const int col0 = (wid & 1) * 64;

    const int ra0 = min(row0 + r,      NN - 1);
    const int ra1 = min(row0 + 16 + r, NN - 1);

    float bv[4];
#pragma unroll
    for (int c = 0; c < 4; ++c) bv[c] = bias[col0 + c * 16 + r];

    f32x4 acc[2][4];
#pragma unroll
    for (int m = 0; m < 2; ++m)
#pragma unroll
        for (int c = 0; c < 4; ++c) acc[m][c] = (f32x4){0.f, 0.f, 0.f, 0.f};

#pragma unroll
    for (int ks = 0; ks < 8; ++ks) {
        const unsigned short* S = (ks < 4) ? Ab : Hb;
        const unsigned short* W = (ks < 4) ? Wlb : Wrb;
        const int kk = (ks & 3) * 32 + kg * 8;
        bf16x8 a0 = *(const bf16x8*)(S + (size_t)ra0 * D + kk);
        bf16x8 a1 = *(const bf16x8*)(S + (size_t)ra1 * D + kk);
        bf16x8 bw[4];
#pragma unroll
        for (int c = 0; c < 4; ++c)
            bw[c] = *(const bf16x8*)(W + (size_t)(col0 + c * 16 + r) * D + kk);
#pragma unroll
        for (int c = 0; c < 4; ++c) {
            acc[0][c] = __builtin_amdgcn_mfma_f32_16x16x32_bf16(a0, bw[c], acc[0][c], 0, 0, 0);
            acc[1][c] = __builtin_amdgcn_mfma_f32_16x16x32_bf16(a1, bw[c], acc[1][c], 0, 0, 0);
        }
    }

    // C/D layout: col = c*16 + (lane&15), row = m*16 + (lane>>4)*4 + q   [m89]
#pragma unroll
    for (int m = 0; m < 2; ++m) {
#pragma unroll
        for (int q = 0; q < 4; ++q) {
            int row = row0 + m * 16 + kg * 4 + q;
            if (row < NN) {
#pragma unroll
                for (int c = 0; c < 4; ++c) {
                    float v = acc[m][c][q] + bv[c];
                    v = v > 0.f ? v : 0.5f * v;
                    int colj = col0 + c * 16 + r;
                    if (OUT_F32) outf[(size_t)row * D + colj] = v;
                    else         outb[(size_t)row * D + colj] = f2b(v);
                }
            }
        }
    }
}

extern "C" void kernel_launch(void* const* d_in, const int* in_sizes, int n_in,
                              void* d_out, int out_size, void* d_ws, size_t ws_size,
                              hipStream_t stream) {
    const float* x   = (const float*)d_in[0];
    const int*   ei  = (const int*)d_in[1];
    const float* W1l = (const float*)d_in[2];
    const float* W1r = (const float*)d_in[3];
    const float* b1  = (const float*)d_in[4];
    const float* W2l = (const float*)d_in[5];
    const float* W2r = (const float*)d_in[6];
    const float* b2  = (const float*)d_in[7];
    float* out = (float*)d_out;

    char* ws = (char*)d_ws;
    size_t off = 0;
    auto alloc = [&](size_t bytes) {
        void* p = ws + off;
        off = (off + bytes + 255) & ~(size_t)255;
        return p;
    };
    int* rowptr = (int*)alloc((NN + 1) * 4);
    int* cursor = (int*)alloc(NN * 4);
    int* bsum   = (int*)alloc(4096);
    int* gcur   = (int*)alloc(512);
    int* col    = (int*)alloc((size_t)NE * 4);
    unsigned short* xb   = (unsigned short*)alloc((size_t)NN * D * 2);
    unsigned short* aggb = (unsigned short*)alloc((size_t)NN * D * 2);
    unsigned short* h1b  = (unsigned short*)alloc((size_t)NN * D * 2);
    unsigned short* wb   = (unsigned short*)alloc((size_t)4 * D * D * 2);
    unsigned short* w1lb = wb;
    unsigned short* w1rb = wb + D * D;
    unsigned short* w2lb = wb + 2 * D * D;
    unsigned short* w2rb = wb + 3 * D * D;
    // ebuf (12.8 MB) aliases h1b (25.6 MB): ebuf dead before h1b is written
    unsigned long long* ebuf = (unsigned long long*)h1b;

    // ---- CSR build ----
    zero_int<<<(NN + 255) / 256, 256, 0, stream>>>(cursor, NN);
    hist_kernel<<<(NE + 255) / 256, 256, 0, stream>>>(ei, cursor);
    scanA<<<NSCAN, 256, 0, stream>>>(cursor, rowptr, bsum);
    scanB<<<1, 128, 0, stream>>>(bsum, NSCAN);
    scanC<<<(NN + 255) / 256, 256, 0, stream>>>(rowptr, bsum, cursor, gcur);
    bin_scatter<<<(NE + BCHUNK - 1) / BCHUNK, 256, 0, stream>>>(ei, gcur, ebuf);
    fill_from_buckets<<<(NE + 255) / 256, 256, 0, stream>>>(ebuf, cursor, col);

    // ---- bf16 conversions ----
    conv_f2b<<<(NN * D / 4 + 255) / 256, 256, 0, stream>>>(x, xb, NN * D);
    conv_w4<<<(4 * D * D / 4 + 255) / 256, 256, 0, stream>>>(W1l, W1r, W2l, W2r, wb);

    // ---- layer 1 ----
    aggregate<<<(NN + 3) / 4, 256, 0, stream>>>(xb, rowptr, col, aggb);
    sage_gemm_mfma<0><<<(NN + 63) / 64, 256, 0, stream>>>(aggb, xb, w1lb, w1rb, b1,
                                                          nullptr, h1b);
    // ---- layer 2 ----
    aggregate<<<(NN + 3) / 4, 256, 0, stream>>>(h1b, rowptr, col, aggb);
    sage_gemm_mfma<1><<<(NN + 63) / 64, 256, 0, stream>>>(aggb, h1b, w2lb, w2rb, b2,
                                                          out, nullptr);
}

// Round 7
// 379.971 us; speedup vs baseline: 2.5748x; 1.0477x over previous
//
#include <hip/hip_runtime.h>
#include <hip/hip_bf16.h>

#define NN 100000
#define NE 1600000
#define D  128
#define SCAN_CHUNK 1024
#define NSCAN ((NN + SCAN_CHUNK - 1) / SCAN_CHUNK)   // 98
#define NB 98          // dst buckets of 1024 nodes (dst>>10)
#define BCHUNK 8192    // edges per bin_scatter block

typedef short bf16x8 __attribute__((ext_vector_type(8)));
typedef float f32x4 __attribute__((ext_vector_type(4)));

static __device__ inline unsigned short f2b(float f) {
    __hip_bfloat16 b = __float2bfloat16(f);   // RNE
    unsigned short u;
    __builtin_memcpy(&u, &b, 2);
    return u;
}

__global__ void zero_int(int* __restrict__ p, int n) {
    int i = blockIdx.x * 256 + threadIdx.x;
    if (i < n) p[i] = 0;
}

// count in-degree: cnt[dst]++
__global__ void hist_kernel(const int* __restrict__ ei, int* __restrict__ cnt) {
    int e = blockIdx.x * 256 + threadIdx.x;
    if (e < NE) atomicAdd(&cnt[ei[NE + e]], 1);
}

// per-1024-chunk exclusive scan, emit chunk sums
__global__ void scanA(const int* __restrict__ cnt, int* __restrict__ rowptr,
                      int* __restrict__ bsum) {
    __shared__ int lds[256];
    int tid  = threadIdx.x;
    int base = blockIdx.x * SCAN_CHUNK + tid * 4;
    int v[4];
#pragma unroll
    for (int i = 0; i < 4; ++i) v[i] = (base + i < NN) ? cnt[base + i] : 0;
    int s = v[0] + v[1] + v[2] + v[3];
    lds[tid] = s;
    __syncthreads();
    for (int off = 1; off < 256; off <<= 1) {
        int t = (tid >= off) ? lds[tid - off] : 0;
        __syncthreads();
        lds[tid] += t;
        __syncthreads();
    }
    int excl = lds[tid] - s;
    if (tid == 255) bsum[blockIdx.x] = lds[255];
    int run = excl;
#pragma unroll
    for (int i = 0; i < 4; ++i) {
        if (base + i < NN) rowptr[base + i] = run;
        run += v[i];
    }
}

// parallel exclusive scan of the 98 chunk sums (one block)
__global__ void scanB(int* __restrict__ bsum, int nb) {
    __shared__ int s[128];
    int t = threadIdx.x;
    int v = (t < nb) ? bsum[t] : 0;
    s[t] = v;
    __syncthreads();
    for (int off = 1; off < 128; off <<= 1) {
        int tv = (t >= off) ? s[t - off] : 0;
        __syncthreads();
        s[t] += tv;
        __syncthreads();
    }
    if (t < nb) bsum[t] = s[t] - v;
}

// finalize rowptr; produce fill cursor (copy) and per-bucket bases gcur
__global__ void scanC(int* __restrict__ rowptr, const int* __restrict__ bsum,
                      int* __restrict__ cursor, int* __restrict__ gcur) {
    int i = blockIdx.x * 256 + threadIdx.x;
    if (i < NN) {
        int v = rowptr[i] + bsum[i / SCAN_CHUNK];
        rowptr[i] = v;
        cursor[i] = v;
        if ((i & 1023) == 0) gcur[i >> 10] = v;   // bucket base = rowptr[b<<10]
    }
    if (i == 0) rowptr[NN] = NE;
}

// Phase B: bin edges by dst>>10 into bucket-grouped (dst,src) pairs.
__global__ __launch_bounds__(256) void bin_scatter(const int* __restrict__ ei,
                                                   int* __restrict__ gcur,
                                                   unsigned long long* __restrict__ ebuf) {
    __shared__ int hist[NB];
    __shared__ int base_s[NB];
    int chunk0 = blockIdx.x * BCHUNK;
    for (int t = threadIdx.x; t < NB; t += 256) hist[t] = 0;
    __syncthreads();
    for (int i = 0; i < BCHUNK; i += 256) {
        int e = chunk0 + i + threadIdx.x;
        if (e < NE) atomicAdd(&hist[ei[NE + e] >> 10], 1);
    }
    __syncthreads();
    for (int t = threadIdx.x; t < NB; t += 256) {
        base_s[t] = atomicAdd(&gcur[t], hist[t]);
        hist[t] = 0;
    }
    __syncthreads();
    for (int i = 0; i < BCHUNK; i += 256) {
        int e = chunk0 + i + threadIdx.x;
        if (e < NE) {
            int s = ei[e];
            int d = ei[NE + e];
            int b = d >> 10;
            int off = atomicAdd(&hist[b], 1);
            ebuf[(size_t)base_s[b] + off] =
                ((unsigned long long)(unsigned)d << 32) | (unsigned)s;
        }
    }
}

// Phase C: edges bucket-grouped; scatter src into CSR col (L2-resident window).
__global__ void fill_from_buckets(const unsigned long long* __restrict__ ebuf,
                                  int* __restrict__ cursor, int* __restrict__ col) {
    int e = blockIdx.x * 256 + threadIdx.x;
    if (e < NE) {
        unsigned long long p = ebuf[e];
        int s = (int)(p & 0xffffffffu);
        int d = (int)(p >> 32);
        int pos = atomicAdd(&cursor[d], 1);
        col[pos] = s;
    }
}

// fp32 -> bf16 conversion, 4 elems/thread
__global__ void conv_f2b(const float* __restrict__ src,
                         unsigned short* __restrict__ dst, int n) {
    int i = (blockIdx.x * 256 + threadIdx.x) * 4;
    if (i + 3 < n) {
        float4 v = *(const float4*)(src + i);
        ushort4 o;
        o.x = f2b(v.x); o.y = f2b(v.y); o.z = f2b(v.z); o.w = f2b(v.w);
        *(ushort4*)(dst + i) = o;
    } else {
        for (; i < n; ++i) dst[i] = f2b(src[i]);
    }
}

// all 4 weight matrices (each D*D) in one launch; dsts contiguous
__global__ void conv_w4(const float* __restrict__ s0, const float* __restrict__ s1,
                        const float* __restrict__ s2, const float* __restrict__ s3,
                        unsigned short* __restrict__ dst) {
    int i = (blockIdx.x * 256 + threadIdx.x) * 4;   // [0, 4*D*D)
    const float* srcs[4] = {s0, s1, s2, s3};
    const float* s = srcs[i >> 14];                 // D*D = 16384
    float4 v = *(const float4*)(s + (i & 16383));
    ushort4 o;
    o.x = f2b(v.x); o.y = f2b(v.y); o.z = f2b(v.z); o.w = f2b(v.w);
    *(ushort4*)(dst + i) = o;
}

// mean aggregation over bf16 features.
// One 64-lane wave per node, split into two 32-lane halves: half h processes
// edges beg+h, beg+h+2, ...; each lane loads uint2 (4 bf16, 8B) so 32 lanes
// cover a 256B row. 8 edges in flight per wave per unroll step. Halves merge
// once at the end via shfl_xor(32).
__global__ __launch_bounds__(256) void aggregate(const unsigned short* __restrict__ hb,
                                                 const int* __restrict__ rowptr,
                                                 const int* __restrict__ col,
                                                 unsigned short* __restrict__ aggb) {
    int node = blockIdx.x * 4 + (threadIdx.x >> 6);
    if (node >= NN) return;
    int lane = threadIdx.x & 63;
    int half = lane >> 5;
    int sl   = lane & 31;
    int beg = rowptr[node], end = rowptr[node + 1];
    const uint2* hp = (const uint2*)hb;   // 32 uint2 per row
    float a0 = 0.f, a1 = 0.f, a2 = 0.f, a3 = 0.f;

    int j = beg + half;
    for (; j + 6 < end; j += 8) {
        int c0 = col[j];
        int c1 = col[j + 2];
        int c2 = col[j + 4];
        int c3 = col[j + 6];
        uint2 v0 = hp[c0 * 32 + sl];
        uint2 v1 = hp[c1 * 32 + sl];
        uint2 v2 = hp[c2 * 32 + sl];
        uint2 v3 = hp[c3 * 32 + sl];
        a0 += __uint_as_float(v0.x << 16) + __uint_as_float(v1.x << 16)
            + __uint_as_float(v2.x << 16) + __uint_as_float(v3.x << 16);
        a1 += __uint_as_float(v0.x & 0xffff0000u) + __uint_as_float(v1.x & 0xffff0000u)
            + __uint_as_float(v2.x & 0xffff0000u) + __uint_as_float(v3.x & 0xffff0000u);
        a2 += __uint_as_float(v0.y << 16) + __uint_as_float(v1.y << 16)
            + __uint_as_float(v2.y << 16) + __uint_as_float(v3.y << 16);
        a3 += __uint_as_float(v0.y & 0xffff0000u) + __uint_as_float(v1.y & 0xffff0000u)
            + __uint_as_float(v2.y & 0xffff0000u) + __uint_as_float(v3.y & 0xffff0000u);
    }
    for (; j < end; j += 2) {
        uint2 v = hp[col[j] * 32 + sl];
        a0 += __uint_as_float(v.x << 16);
        a1 += __uint_as_float(v.x & 0xffff0000u);
        a2 += __uint_as_float(v.y << 16);
        a3 += __uint_as_float(v.y & 0xffff0000u);
    }

    // merge the two halves (lane L and L+32 hold the same 4 channels)
    a0 += __shfl_xor(a0, 32);
    a1 += __shfl_xor(a1, 32);
    a2 += __shfl_xor(a2, 32);
    a3 += __shfl_xor(a3, 32);

    int deg = end - beg;
    float inv = 1.0f / (float)(deg > 1 ? deg : 1);
    if (half == 0) {
        uint2 o;
        o.x = (unsigned)f2b(a0 * inv) | ((unsigned)f2b(a1 * inv) << 16);
        o.y = (unsigned)f2b(a2 * inv) | ((unsigned)f2b(a3 * inv) << 16);
        ((uint2*)aggb)[(size_t)node * 32 + sl] = o;
    }
}

// out[n][j] = leaky_relu( sum_k agg[n][k]*Wl[j][k] + h[n][k]*Wr[j][k] + b[j], 0.5 )
// MFMA 16x16x32 bf16. Block = 256 thr = 4 waves (2x2), block tile 64 rows x 128 cols,
// wave tile 32 rows x 64 cols. No LDS, no barriers: fragments load direct from global.
template <int OUT_F32>
__global__ __launch_bounds__(256) void sage_gemm_mfma(
    const unsigned short* __restrict__ Ab,   // [NN][128] aggregated
    const unsigned short* __restrict__ Hb,   // [NN][128] root
    const unsigned short* __restrict__ Wlb,  // [128][128], row j contiguous in k
    const unsigned short* __restrict__ Wrb,
    const float* __restrict__ bias,
    float* __restrict__ outf,
    unsigned short* __restrict__ outb)
{
    const int lane = threadIdx.x & 63;
    const int wid  = threadIdx.x >> 6;
    const int r  = lane & 15;
    const int kg = lane >> 4;
    const int row0 = blockIdx.x * 64 + (wid >> 1) * 32;
    const int col0 = (wid & 1) * 64;

    const int ra0 = min(row0 + r,      NN - 1);
    const int ra1 = min(row0 + 16 + r, NN - 1);

    float bv[4];
#pragma unroll
    for (int c = 0; c < 4; ++c) bv[c] = bias[col0 + c * 16 + r];

    f32x4 acc[2][4];
#pragma unroll
    for (int m = 0; m < 2; ++m)
#pragma unroll
        for (int c = 0; c < 4; ++c) acc[m][c] = (f32x4){0.f, 0.f, 0.f, 0.f};

#pragma unroll
    for (int ks = 0; ks < 8; ++ks) {
        const unsigned short* S = (ks < 4) ? Ab : Hb;
        const unsigned short* W = (ks < 4) ? Wlb : Wrb;
        const int kk = (ks & 3) * 32 + kg * 8;
        bf16x8 a0 = *(const bf16x8*)(S + (size_t)ra0 * D + kk);
        bf16x8 a1 = *(const bf16x8*)(S + (size_t)ra1 * D + kk);
        bf16x8 bw[4];
#pragma unroll
        for (int c = 0; c < 4; ++c)
            bw[c] = *(const bf16x8*)(W + (size_t)(col0 + c * 16 + r) * D + kk);
#pragma unroll
        for (int c = 0; c < 4; ++c) {
            acc[0][c] = __builtin_amdgcn_mfma_f32_16x16x32_bf16(a0, bw[c], acc[0][c], 0, 0, 0);
            acc[1][c] = __builtin_amdgcn_mfma_f32_16x16x32_bf16(a1, bw[c], acc[1][c], 0, 0, 0);
        }
    }

    // C/D layout: col = c*16 + (lane&15), row = m*16 + (lane>>4)*4 + q   [m89]
#pragma unroll
    for (int m = 0; m < 2; ++m) {
#pragma unroll
        for (int q = 0; q < 4; ++q) {
            int row = row0 + m * 16 + kg * 4 + q;
            if (row < NN) {
#pragma unroll
                for (int c = 0; c < 4; ++c) {
                    float v = acc[m][c][q] + bv[c];
                    v = v > 0.f ? v : 0.5f * v;
                    int colj = col0 + c * 16 + r;
                    if (OUT_F32) outf[(size_t)row * D + colj] = v;
                    else         outb[(size_t)row * D + colj] = f2b(v);
                }
            }
        }
    }
}

extern "C" void kernel_launch(void* const* d_in, const int* in_sizes, int n_in,
                              void* d_out, int out_size, void* d_ws, size_t ws_size,
                              hipStream_t stream) {
    const float* x   = (const float*)d_in[0];
    const int*   ei  = (const int*)d_in[1];
    const float* W1l = (const float*)d_in[2];
    const float* W1r = (const float*)d_in[3];
    const float* b1  = (const float*)d_in[4];
    const float* W2l = (const float*)d_in[5];
    const float* W2r = (const float*)d_in[6];
    const float* b2  = (const float*)d_in[7];
    float* out = (float*)d_out;

    char* ws = (char*)d_ws;
    size_t off = 0;
    auto alloc = [&](size_t bytes) {
        void* p = ws + off;
        off = (off + bytes + 255) & ~(size_t)255;
        return p;
    };
    int* rowptr = (int*)alloc((NN + 1) * 4);
    int* cursor = (int*)alloc(NN * 4);
    int* bsum   = (int*)alloc(4096);
    int* gcur   = (int*)alloc(512);
    int* col    = (int*)alloc((size_t)NE * 4);
    unsigned short* xb   = (unsigned short*)alloc((size_t)NN * D * 2);
    unsigned short* aggb = (unsigned short*)alloc((size_t)NN * D * 2);
    unsigned short* h1b  = (unsigned short*)alloc((size_t)NN * D * 2);
    unsigned short* wb   = (unsigned short*)alloc((size_t)4 * D * D * 2);
    unsigned short* w1lb = wb;
    unsigned short* w1rb = wb + D * D;
    unsigned short* w2lb = wb + 2 * D * D;
    unsigned short* w2rb = wb + 3 * D * D;
    // ebuf (12.8 MB) aliases h1b (25.6 MB): ebuf dead before h1b is written
    unsigned long long* ebuf = (unsigned long long*)h1b;

    // ---- CSR build ----
    zero_int<<<(NN + 255) / 256, 256, 0, stream>>>(cursor, NN);
    hist_kernel<<<(NE + 255) / 256, 256, 0, stream>>>(ei, cursor);
    scanA<<<NSCAN, 256, 0, stream>>>(cursor, rowptr, bsum);
    scanB<<<1, 128, 0, stream>>>(bsum, NSCAN);
    scanC<<<(NN + 255) / 256, 256, 0, stream>>>(rowptr, bsum, cursor, gcur);
    bin_scatter<<<(NE + BCHUNK - 1) / BCHUNK, 256, 0, stream>>>(ei, gcur, ebuf);
    fill_from_buckets<<<(NE + 255) / 256, 256, 0, stream>>>(ebuf, cursor, col);

    // ---- bf16 conversions ----
    conv_f2b<<<(NN * D / 4 + 255) / 256, 256, 0, stream>>>(x, xb, NN * D);
    conv_w4<<<(4 * D * D / 4 + 255) / 256, 256, 0, stream>>>(W1l, W1r, W2l, W2r, wb);

    // ---- layer 1 ----
    aggregate<<<(NN + 3) / 4, 256, 0, stream>>>(xb, rowptr, col, aggb);
    sage_gemm_mfma<0><<<(NN + 63) / 64, 256, 0, stream>>>(aggb, xb, w1lb, w1rb, b1,
                                                          nullptr, h1b);
    // ---- layer 2 ----
    aggregate<<<(NN + 3) / 4, 256, 0, stream>>>(h1b, rowptr, col, aggb);
    sage_gemm_mfma<1><<<(NN + 63) / 64, 256, 0, stream>>>(aggb, h1b, w2lb, w2rb, b2,
                                                          out, nullptr);
}

// Round 8
// 375.773 us; speedup vs baseline: 2.6036x; 1.0112x over previous
//
#include <hip/hip_runtime.h>
#include <hip/hip_bf16.h>

#define NN 100000
#define NE 1600000
#define D  128
#define SCAN_CHUNK 1024
#define NSCAN ((NN + SCAN_CHUNK - 1) / SCAN_CHUNK)   // 98
#define NB 98          // dst buckets of 1024 nodes (dst>>10)
#define BCHUNK 8192    // edges per bin_scatter block

typedef short bf16x8 __attribute__((ext_vector_type(8)));
typedef float f32x4 __attribute__((ext_vector_type(4)));

static __device__ inline unsigned short f2b(float f) {
    __hip_bfloat16 b = __float2bfloat16(f);   // RNE
    unsigned short u;
    __builtin_memcpy(&u, &b, 2);
    return u;
}

// coarse bucket histogram: 98 buckets, LDS-aggregated, ~19K global atomics total
__global__ __launch_bounds__(256) void bucket_count(const int* __restrict__ ei,
                                                    int* __restrict__ bcnt) {
    __shared__ int hist[NB];
    int chunk0 = blockIdx.x * BCHUNK;
    for (int t = threadIdx.x; t < NB; t += 256) hist[t] = 0;
    __syncthreads();
    for (int i = 0; i < BCHUNK; i += 256) {
        int e = chunk0 + i + threadIdx.x;
        if (e < NE) atomicAdd(&hist[ei[NE + e] >> 10], 1);
    }
    __syncthreads();
    for (int t = threadIdx.x; t < NB; t += 256)
        if (hist[t]) atomicAdd(&bcnt[t], hist[t]);
}

// per-node counts from bucket-grouped edges: atomics land in a rolling 4KB
// window of cnt -> cache-coalesced, unlike random per-node atomics (49.9MB
// of HBM write-through measured in round 7).
__global__ void hist2(const unsigned long long* __restrict__ ebuf,
                      int* __restrict__ cnt) {
    int e = blockIdx.x * 256 + threadIdx.x;
    if (e < NE) atomicAdd(&cnt[(int)(ebuf[e] >> 32)], 1);
}

// per-1024-chunk exclusive scan, emit chunk sums
__global__ void scanA(const int* __restrict__ cnt, int* __restrict__ rowptr,
                      int* __restrict__ bsum) {
    __shared__ int lds[256];
    int tid  = threadIdx.x;
    int base = blockIdx.x * SCAN_CHUNK + tid * 4;
    int v[4];
#pragma unroll
    for (int i = 0; i < 4; ++i) v[i] = (base + i < NN) ? cnt[base + i] : 0;
    int s = v[0] + v[1] + v[2] + v[3];
    lds[tid] = s;
    __syncthreads();
    for (int off = 1; off < 256; off <<= 1) {
        int t = (tid >= off) ? lds[tid - off] : 0;
        __syncthreads();
        lds[tid] += t;
        __syncthreads();
    }
    int excl = lds[tid] - s;
    if (tid == 255) bsum[blockIdx.x] = lds[255];
    int run = excl;
#pragma unroll
    for (int i = 0; i < 4; ++i) {
        if (base + i < NN) rowptr[base + i] = run;
        run += v[i];
    }
}

// parallel exclusive scan of <=128 entries in place; optional 2nd output copy
__global__ void scanB(int* __restrict__ a, int* __restrict__ out2, int nb) {
    __shared__ int s[128];
    int t = threadIdx.x;
    int v = (t < nb) ? a[t] : 0;
    s[t] = v;
    __syncthreads();
    for (int off = 1; off < 128; off <<= 1) {
        int tv = (t >= off) ? s[t - off] : 0;
        __syncthreads();
        s[t] += tv;
        __syncthreads();
    }
    if (t < nb) {
        int excl = s[t] - v;
        a[t] = excl;
        if (out2) out2[t] = excl;
    }
}

// finalize rowptr; produce fill cursor (copy)
__global__ void scanC(int* __restrict__ rowptr, const int* __restrict__ bsum,
                      int* __restrict__ cursor) {
    int i = blockIdx.x * 256 + threadIdx.x;
    if (i < NN) {
        int v = rowptr[i] + bsum[i / SCAN_CHUNK];
        rowptr[i] = v;
        cursor[i] = v;
    }
    if (i == 0) rowptr[NN] = NE;
}

// Phase B: bin edges by dst>>10 into bucket-grouped (dst,src) pairs.
__global__ __launch_bounds__(256) void bin_scatter(const int* __restrict__ ei,
                                                   int* __restrict__ gcur,
                                                   unsigned long long* __restrict__ ebuf) {
    __shared__ int hist[NB];
    __shared__ int base_s[NB];
    int chunk0 = blockIdx.x * BCHUNK;
    for (int t = threadIdx.x; t < NB; t += 256) hist[t] = 0;
    __syncthreads();
    for (int i = 0; i < BCHUNK; i += 256) {
        int e = chunk0 + i + threadIdx.x;
        if (e < NE) atomicAdd(&hist[ei[NE + e] >> 10], 1);
    }
    __syncthreads();
    for (int t = threadIdx.x; t < NB; t += 256) {
        base_s[t] = atomicAdd(&gcur[t], hist[t]);
        hist[t] = 0;
    }
    __syncthreads();
    for (int i = 0; i < BCHUNK; i += 256) {
        int e = chunk0 + i + threadIdx.x;
        if (e < NE) {
            int s = ei[e];
            int d = ei[NE + e];
            int b = d >> 10;
            int off = atomicAdd(&hist[b], 1);
            ebuf[(size_t)base_s[b] + off] =
                ((unsigned long long)(unsigned)d << 32) | (unsigned)s;
        }
    }
}

// Phase C: edges bucket-grouped; scatter src into CSR col (L2-resident window).
__global__ void fill_from_buckets(const unsigned long long* __restrict__ ebuf,
                                  int* __restrict__ cursor, int* __restrict__ col) {
    int e = blockIdx.x * 256 + threadIdx.x;
    if (e < NE) {
        unsigned long long p = ebuf[e];
        int s = (int)(p & 0xffffffffu);
        int d = (int)(p >> 32);
        int pos = atomicAdd(&cursor[d], 1);
        col[pos] = s;
    }
}

// fp32 -> bf16 conversion, 4 elems/thread
__global__ void conv_f2b(const float* __restrict__ src,
                         unsigned short* __restrict__ dst, int n) {
    int i = (blockIdx.x * 256 + threadIdx.x) * 4;
    if (i + 3 < n) {
        float4 v = *(const float4*)(src + i);
        ushort4 o;
        o.x = f2b(v.x); o.y = f2b(v.y); o.z = f2b(v.z); o.w = f2b(v.w);
        *(ushort4*)(dst + i) = o;
    } else {
        for (; i < n; ++i) dst[i] = f2b(src[i]);
    }
}

// all 4 weight matrices (each D*D) in one launch; dsts contiguous
__global__ void conv_w4(const float* __restrict__ s0, const float* __restrict__ s1,
                        const float* __restrict__ s2, const float* __restrict__ s3,
                        unsigned short* __restrict__ dst) {
    int i = (blockIdx.x * 256 + threadIdx.x) * 4;   // [0, 4*D*D)
    const float* srcs[4] = {s0, s1, s2, s3};
    const float* s = srcs[i >> 14];                 // D*D = 16384
    float4 v = *(const float4*)(s + (i & 16383));
    ushort4 o;
    o.x = f2b(v.x); o.y = f2b(v.y); o.z = f2b(v.z); o.w = f2b(v.w);
    *(ushort4*)(dst + i) = o;
}

// mean aggregation over bf16 features; two 32-lane halves per wave, uint2/lane
__global__ __launch_bounds__(256) void aggregate(const unsigned short* __restrict__ hb,
                                                 const int* __restrict__ rowptr,
                                                 const int* __restrict__ col,
                                                 unsigned short* __restrict__ aggb) {
    int node = blockIdx.x * 4 + (threadIdx.x >> 6);
    if (node >= NN) return;
    int lane = threadIdx.x & 63;
    int half = lane >> 5;
    int sl   = lane & 31;
    int beg = rowptr[node], end = rowptr[node + 1];
    const uint2* hp = (const uint2*)hb;   // 32 uint2 per row
    float a0 = 0.f, a1 = 0.f, a2 = 0.f, a3 = 0.f;

    int j = beg + half;
    for (; j + 6 < end; j += 8) {
        int c0 = col[j];
        int c1 = col[j + 2];
        int c2 = col[j + 4];
        int c3 = col[j + 6];
        uint2 v0 = hp[c0 * 32 + sl];
        uint2 v1 = hp[c1 * 32 + sl];
        uint2 v2 = hp[c2 * 32 + sl];
        uint2 v3 = hp[c3 * 32 + sl];
        a0 += __uint_as_float(v0.x << 16) + __uint_as_float(v1.x << 16)
            + __uint_as_float(v2.x << 16) + __uint_as_float(v3.x << 16);
        a1 += __uint_as_float(v0.x & 0xffff0000u) + __uint_as_float(v1.x & 0xffff0000u)
            + __uint_as_float(v2.x & 0xffff0000u) + __uint_as_float(v3.x & 0xffff0000u);
        a2 += __uint_as_float(v0.y << 16) + __uint_as_float(v1.y << 16)
            + __uint_as_float(v2.y << 16) + __uint_as_float(v3.y << 16);
        a3 += __uint_as_float(v0.y & 0xffff0000u) + __uint_as_float(v1.y & 0xffff0000u)
            + __uint_as_float(v2.y & 0xffff0000u) + __uint_as_float(v3.y & 0xffff0000u);
    }
    for (; j < end; j += 2) {
        uint2 v = hp[col[j] * 32 + sl];
        a0 += __uint_as_float(v.x << 16);
        a1 += __uint_as_float(v.x & 0xffff0000u);
        a2 += __uint_as_float(v.y << 16);
        a3 += __uint_as_float(v.y & 0xffff0000u);
    }

    a0 += __shfl_xor(a0, 32);
    a1 += __shfl_xor(a1, 32);
    a2 += __shfl_xor(a2, 32);
    a3 += __shfl_xor(a3, 32);

    int deg = end - beg;
    float inv = 1.0f / (float)(deg > 1 ? deg : 1);
    if (half == 0) {
        uint2 o;
        o.x = (unsigned)f2b(a0 * inv) | ((unsigned)f2b(a1 * inv) << 16);
        o.y = (unsigned)f2b(a2 * inv) | ((unsigned)f2b(a3 * inv) << 16);
        ((uint2*)aggb)[(size_t)node * 32 + sl] = o;
    }
}

// out[n][j] = leaky_relu( sum_k agg[n][k]*Wl[j][k] + h[n][k]*Wr[j][k] + b[j], 0.5 )
// MFMA 16x16x32 bf16. Block = 256 thr = 4 waves (2x2), block tile 64 rows x 128 cols,
// wave tile 32 rows x 64 cols. No LDS, no barriers: fragments load direct from global.
template <int OUT_F32>
__global__ __launch_bounds__(256) void sage_gemm_mfma(
    const unsigned short* __restrict__ Ab,   // [NN][128] aggregated
    const unsigned short* __restrict__ Hb,   // [NN][128] root
    const unsigned short* __restrict__ Wlb,  // [128][128], row j contiguous in k
    const unsigned short* __restrict__ Wrb,
    const float* __restrict__ bias,
    float* __restrict__ outf,
    unsigned short* __restrict__ outb)
{
    const int lane = threadIdx.x & 63;
    const int wid  = threadIdx.x >> 6;
    const int r  = lane & 15;
    const int kg = lane >> 4;
    const int row0 = blockIdx.x * 64 + (wid >> 1) * 32;
    const int col0 = (wid & 1) * 64;

    const int ra0 = min(row0 + r,      NN - 1);
    const int ra1 = min(row0 + 16 + r, NN - 1);

    float bv[4];
#pragma unroll
    for (int c = 0; c < 4; ++c) bv[c] = bias[col0 + c * 16 + r];

    f32x4 acc[2][4];
#pragma unroll
    for (int m = 0; m < 2; ++m)
#pragma unroll
        for (int c = 0; c < 4; ++c) acc[m][c] = (f32x4){0.f, 0.f, 0.f, 0.f};

#pragma unroll
    for (int ks = 0; ks < 8; ++ks) {
        const unsigned short* S = (ks < 4) ? Ab : Hb;
        const unsigned short* W = (ks < 4) ? Wlb : Wrb;
        const int kk = (ks & 3) * 32 + kg * 8;
        bf16x8 a0 = *(const bf16x8*)(S + (size_t)ra0 * D + kk);
        bf16x8 a1 = *(const bf16x8*)(S + (size_t)ra1 * D + kk);
        bf16x8 bw[4];
#pragma unroll
        for (int c = 0; c < 4; ++c)
            bw[c] = *(const bf16x8*)(W + (size_t)(col0 + c * 16 + r) * D + kk);
#pragma unroll
        for (int c = 0; c < 4; ++c) {
            acc[0][c] = __builtin_amdgcn_mfma_f32_16x16x32_bf16(a0, bw[c], acc[0][c], 0, 0, 0);
            acc[1][c] = __builtin_amdgcn_mfma_f32_16x16x32_bf16(a1, bw[c], acc[1][c], 0, 0, 0);
        }
    }

    // C/D layout: col = c*16 + (lane&15), row = m*16 + (lane>>4)*4 + q   [m89]
#pragma unroll
    for (int m = 0; m < 2; ++m) {
#pragma unroll
        for (int q = 0; q < 4; ++q) {
            int row = row0 + m * 16 + kg * 4 + q;
            if (row < NN) {
#pragma unroll
                for (int c = 0; c < 4; ++c) {
                    float v = acc[m][c][q] + bv[c];
                    v = v > 0.f ? v : 0.5f * v;
                    int colj = col0 + c * 16 + r;
                    if (OUT_F32) outf[(size_t)row * D + colj] = v;
                    else         outb[(size_t)row * D + colj] = f2b(v);
                }
            }
        }
    }
}

extern "C" void kernel_launch(void* const* d_in, const int* in_sizes, int n_in,
                              void* d_out, int out_size, void* d_ws, size_t ws_size,
                              hipStream_t stream) {
    const float* x   = (const float*)d_in[0];
    const int*   ei  = (const int*)d_in[1];
    const float* W1l = (const float*)d_in[2];
    const float* W1r = (const float*)d_in[3];
    const float* b1  = (const float*)d_in[4];
    const float* W2l = (const float*)d_in[5];
    const float* W2r = (const float*)d_in[6];
    const float* b2  = (const float*)d_in[7];
    float* out = (float*)d_out;

    char* ws = (char*)d_ws;
    size_t off = 0;
    auto alloc = [&](size_t bytes) {
        void* p = ws + off;
        off = (off + bytes + 255) & ~(size_t)255;
        return p;
    };
    int* rowptr = (int*)alloc((NN + 1) * 4);
    int* cursor = (int*)alloc(NN * 4);          // doubles as per-node cnt
    int* bsum   = (int*)alloc(4096);
    int* bcnt   = (int*)alloc(512);
    int* gcur   = (int*)alloc(512);
    int* col    = (int*)alloc((size_t)NE * 4);
    unsigned short* xb   = (unsigned short*)alloc((size_t)NN * D * 2);
    unsigned short* aggb = (unsigned short*)alloc((size_t)NN * D * 2);
    unsigned short* h1b  = (unsigned short*)alloc((size_t)NN * D * 2);
    unsigned short* wb   = (unsigned short*)alloc((size_t)4 * D * D * 2);
    unsigned short* w1lb = wb;
    unsigned short* w1rb = wb + D * D;
    unsigned short* w2lb = wb + 2 * D * D;
    unsigned short* w2rb = wb + 3 * D * D;
    // ebuf (12.8 MB) aliases h1b (25.6 MB): ebuf dead before h1b is written
    unsigned long long* ebuf = (unsigned long long*)h1b;

    // ---- CSR build (no random per-node atomics anywhere) ----
    hipMemsetAsync(cursor, 0, (size_t)NN * 4, stream);
    hipMemsetAsync(bcnt, 0, NB * 4, stream);
    bucket_count<<<(NE + BCHUNK - 1) / BCHUNK, 256, 0, stream>>>(ei, bcnt);
    scanB<<<1, 128, 0, stream>>>(bcnt, gcur, NB);
    bin_scatter<<<(NE + BCHUNK - 1) / BCHUNK, 256, 0, stream>>>(ei, gcur, ebuf);
    hist2<<<(NE + 255) / 256, 256, 0, stream>>>(ebuf, cursor);
    scanA<<<NSCAN, 256, 0, stream>>>(cursor, rowptr, bsum);
    scanB<<<1, 128, 0, stream>>>(bsum, nullptr, NSCAN);
    scanC<<<(NN + 255) / 256, 256, 0, stream>>>(rowptr, bsum, cursor);
    fill_from_buckets<<<(NE + 255) / 256, 256, 0, stream>>>(ebuf, cursor, col);

    // ---- bf16 conversions ----
    conv_f2b<<<(NN * D / 4 + 255) / 256, 256, 0, stream>>>(x, xb, NN * D);
    conv_w4<<<(4 * D * D / 4 + 255) / 256, 256, 0, stream>>>(W1l, W1r, W2l, W2r, wb);

    // ---- layer 1 ----
    aggregate<<<(NN + 3) / 4, 256, 0, stream>>>(xb, rowptr, col, aggb);
    sage_gemm_mfma<0><<<(NN + 63) / 64, 256, 0, stream>>>(aggb, xb, w1lb, w1rb, b1,
                                                          nullptr, h1b);
    // ---- layer 2 ----
    aggregate<<<(NN + 3) / 4, 256, 0, stream>>>(h1b, rowptr, col, aggb);
    sage_gemm_mfma<1><<<(NN + 63) / 64, 256, 0, stream>>>(aggb, h1b, w2lb, w2rb, b2,
                                                          out, nullptr);
}